// Round 5
// baseline (62.943 us; speedup 1.0000x reference)
//
#include <hip/hip_runtime.h>

// Reprojection: x[N=1024, M=16384, 3] f32 points, c[N, 3, 4] f32 camera mats.
// out[n,m,i] = (sum_k [x|1][n,m,k] * c[n,i,k]) for i=0,1 divided by i=2 term.
//
// NUMERICS: harness ref is numpy FLOAT32. Denominator crosses zero (worst
// |den| ~1.5e-7, partials O(1)) so the ref there is determined entirely by
// its f32 rounding SEQUENCE. numpy einsum inner loop (contig_contig_
// outstride0_two, count=4) with SSE3 baseline (vstep=4) takes the SIMD path:
//   vaccum = muladd(a,b,0)  -> separately rounded products p_k = r(a_k*b_k)
//   npyv_sum_f32 (hadd x2)  -> PAIRWISE sum r(r(p0+p1) + r(p2+p3)), p3 = c3
// Evidence: r1/r3 contracted-FMA tree absmax 8.45e6 (HIP __fmul_rn is plain
// a*b and clang CONTRACTS it -> r3 == r1 bit-identical); r4 scalar FMA chain
// 3.93e6; r2 f64 6.75e6. All other candidate sequences falsified.
// Products are done via inline-asm v_mul_f32 (uncontractable); adds are
// explicitly parenthesized (clang preserves FP order without fast-math).
//
// Memory-bound: 192 MiB in + 128 MiB out => ~51 us at 6.3 TB/s.

#define NN 1024
#define MM 16384

// Separately-rounded f32 multiply the compiler cannot fuse into an FMA.
__device__ __forceinline__ float mul_sep(float a, float b) {
    float r;
    asm("v_mul_f32 %0, %1, %2" : "=v"(r) : "v"(a), "v"(b));
    return r;
}

// numpy SSE3 einsum sequence: separate products, pairwise adds.
__device__ __forceinline__ float row_dot(float X, float Y, float Z,
                                         float c0, float c1, float c2, float c3)
{
    const float p0 = mul_sep(X, c0);
    const float p1 = mul_sep(Y, c1);
    const float p2 = mul_sep(Z, c2);
    const float s01 = p0 + p1;        // r(p0+p1)
    const float s23 = p2 + c3;        // r(p2+c3)   (p3 = r(1*c3) = c3)
    return s01 + s23;                 // r(s01+s23)
}

// 256 threads/block, 4 points/thread => 1024 points/block, 16 blocks per n.
__global__ __launch_bounds__(256) void reproj_kernel(
    const float* __restrict__ x,
    const float* __restrict__ c,
    float* __restrict__ out)
{
    const int n     = blockIdx.x >> 4;        // which batch row
    const int chunk = blockIdx.x & 15;        // which 1024-point chunk
    const int m0    = chunk * 1024 + threadIdx.x * 4;  // first point index

    // Camera matrix for this n: 12 floats, broadcast from L1/L2.
    const float* cn = c + (size_t)n * 12;
    const float c00 = cn[0],  c01 = cn[1],  c02 = cn[2],  c03 = cn[3];
    const float c10 = cn[4],  c11 = cn[5],  c12 = cn[6],  c13 = cn[7];
    const float c20 = cn[8],  c21 = cn[9],  c22 = cn[10], c23 = cn[11];

    // 4 points = 12 floats = 3 x float4, fully coalesced, 16B-aligned.
    const float4* __restrict__ xin =
        reinterpret_cast<const float4*>(x + (size_t)n * (MM * 3) + (size_t)m0 * 3);
    const float4 a = xin[0];
    const float4 b = xin[1];
    const float4 d = xin[2];

    // points: p0=(a.x,a.y,a.z) p1=(a.w,b.x,b.y) p2=(b.z,b.w,d.x) p3=(d.y,d.z,d.w)
    const float px[4] = {a.x, a.w, b.z, d.y};
    const float py[4] = {a.y, b.x, b.w, d.z};
    const float pz[4] = {a.z, b.y, d.x, d.w};

    float res[8];
#pragma unroll
    for (int i = 0; i < 4; ++i) {
        const float xp0 = row_dot(px[i], py[i], pz[i], c00, c01, c02, c03);
        const float xp1 = row_dot(px[i], py[i], pz[i], c10, c11, c12, c13);
        const float xp2 = row_dot(px[i], py[i], pz[i], c20, c21, c22, c23);
        // IEEE correctly-rounded f32 division (matches numpy vdivps).
        res[2 * i + 0] = xp0 / xp2;
        res[2 * i + 1] = xp1 / xp2;
    }

    // 4 points * 2 floats = 8 floats = 2 x float4, 32B-aligned.
    float4* __restrict__ o =
        reinterpret_cast<float4*>(out + (size_t)n * (MM * 2) + (size_t)m0 * 2);
    o[0] = make_float4(res[0], res[1], res[2], res[3]);
    o[1] = make_float4(res[4], res[5], res[6], res[7]);
}

extern "C" void kernel_launch(void* const* d_in, const int* in_sizes, int n_in,
                              void* d_out, int out_size, void* d_ws, size_t ws_size,
                              hipStream_t stream) {
    const float* x = (const float*)d_in[0];
    const float* c = (const float*)d_in[1];
    float* out = (float*)d_out;

    // 1024 n * 16 blocks each = 16384 blocks, 256 threads.
    dim3 grid(NN * 16);
    dim3 block(256);
    reproj_kernel<<<grid, block, 0, stream>>>(x, c, out);
}

// Round 7
// 62.275 us; speedup vs baseline: 1.0107x; 1.0107x over previous
//
#include <hip/hip_runtime.h>

// Reprojection: x[N=1024, M=16384, 3] f32 points, c[N, 3, 4] f32 camera mats.
// out[n,m,i] = (sum_k [x|1][n,m,k] * c[n,i,k]) for i=0,1 divided by i=2 term.
//
// NUMERICS (load-bearing, do not touch): harness ref is numpy FLOAT32.
// Denominator crosses zero (worst |den| ~1.5e-7, partials O(1)) so the ref
// there is determined by its f32 rounding SEQUENCE. numpy einsum inner loop
// (contig_contig_outstride0_two, count=4, SSE3 baseline, vstep=4) SIMD path:
//   products p_k = r(a_k*b_k)  (muladd with 0 addend -> plain rounded mul)
//   npyv_sum_f32 (hadd x2)     -> pairwise r(r(p0+p1) + r(p2+p3)), p3 = c3
// Implemented with inline-asm v_mul_f32 (uncontractable) + ordered adds.
// Round-5 result: PASSED, absmax 4.0 (vs threshold 3.9e5).
// Falsified alternatives: clang FMA tree 8.45e6, f64 6.75e6, scalar FMA
// chain 3.93e6.
//
// PERF: memory-bound. 201 MB read + 134 MB write. Round 5: 62.9 us =
// 5.33 TB/s (85% of copy ceiling). This round: non-temporal output stores
// (via native clang vector type — HIP float4* is rejected by the builtin)
// so the write stream doesn't displace x (192 MiB < 256 MiB L3) -> x can
// stay L3-resident across timed replays.

#define NN 1024
#define MM 16384

typedef float f32x4 __attribute__((ext_vector_type(4)));

// Separately-rounded f32 multiply the compiler cannot fuse into an FMA.
__device__ __forceinline__ float mul_sep(float a, float b) {
    float r;
    asm("v_mul_f32 %0, %1, %2" : "=v"(r) : "v"(a), "v"(b));
    return r;
}

// numpy SSE3 einsum sequence: separate products, pairwise adds.
__device__ __forceinline__ float row_dot(float X, float Y, float Z,
                                         float c0, float c1, float c2, float c3)
{
    const float p0 = mul_sep(X, c0);
    const float p1 = mul_sep(Y, c1);
    const float p2 = mul_sep(Z, c2);
    const float s01 = p0 + p1;        // r(p0+p1)
    const float s23 = p2 + c3;        // r(p2+c3)   (p3 = r(1*c3) = c3)
    return s01 + s23;                 // r(s01+s23)
}

// 256 threads/block, 4 points/thread => 1024 points/block, 16 blocks per n.
__global__ __launch_bounds__(256) void reproj_kernel(
    const float* __restrict__ x,
    const float* __restrict__ c,
    float* __restrict__ out)
{
    const int n     = blockIdx.x >> 4;        // which batch row
    const int chunk = blockIdx.x & 15;        // which 1024-point chunk
    const int m0    = chunk * 1024 + threadIdx.x * 4;  // first point index

    // Camera matrix for this n: 12 floats, broadcast from L1/L2.
    const float* cn = c + (size_t)n * 12;
    const float c00 = cn[0],  c01 = cn[1],  c02 = cn[2],  c03 = cn[3];
    const float c10 = cn[4],  c11 = cn[5],  c12 = cn[6],  c13 = cn[7];
    const float c20 = cn[8],  c21 = cn[9],  c22 = cn[10], c23 = cn[11];

    // 4 points = 12 floats = 3 x float4 per thread; the three loads jointly
    // cover a contiguous 3072B span per wave (no HBM over-fetch).
    const float4* __restrict__ xin =
        reinterpret_cast<const float4*>(x + (size_t)n * (MM * 3) + (size_t)m0 * 3);
    const float4 a = xin[0];
    const float4 b = xin[1];
    const float4 d = xin[2];

    // points: p0=(a.x,a.y,a.z) p1=(a.w,b.x,b.y) p2=(b.z,b.w,d.x) p3=(d.y,d.z,d.w)
    const float px[4] = {a.x, a.w, b.z, d.y};
    const float py[4] = {a.y, b.x, b.w, d.z};
    const float pz[4] = {a.z, b.y, d.x, d.w};

    float res[8];
#pragma unroll
    for (int i = 0; i < 4; ++i) {
        const float xp0 = row_dot(px[i], py[i], pz[i], c00, c01, c02, c03);
        const float xp1 = row_dot(px[i], py[i], pz[i], c10, c11, c12, c13);
        const float xp2 = row_dot(px[i], py[i], pz[i], c20, c21, c22, c23);
        // IEEE correctly-rounded f32 division (matches numpy vdivps).
        res[2 * i + 0] = xp0 / xp2;
        res[2 * i + 1] = xp1 / xp2;
    }

    // 4 points * 2 floats = 8 floats = 2 x 16B stores. Non-temporal:
    // streaming write-once data must not displace the x read stream from L3.
    f32x4* __restrict__ o =
        reinterpret_cast<f32x4*>(out + (size_t)n * (MM * 2) + (size_t)m0 * 2);
    const f32x4 o0 = {res[0], res[1], res[2], res[3]};
    const f32x4 o1 = {res[4], res[5], res[6], res[7]};
    __builtin_nontemporal_store(o0, o);
    __builtin_nontemporal_store(o1, o + 1);
}

extern "C" void kernel_launch(void* const* d_in, const int* in_sizes, int n_in,
                              void* d_out, int out_size, void* d_ws, size_t ws_size,
                              hipStream_t stream) {
    const float* x = (const float*)d_in[0];
    const float* c = (const float*)d_in[1];
    float* out = (float*)d_out;

    // 1024 n * 16 blocks each = 16384 blocks, 256 threads.
    dim3 grid(NN * 16);
    dim3 block(256);
    reproj_kernel<<<grid, block, 0, stream>>>(x, c, out);
}